// Round 2
// baseline (398.635 us; speedup 1.0000x reference)
//
#include <hip/hip_runtime.h>

#define BATCH   4
#define SEQLEN  4096
#define NHEADS  32
#define PDIM    64
#define NDIM    16
#define CHUNK   64
#define NCHUNK  64   // SEQLEN / CHUNK
#define PHALF   32

typedef short v8s __attribute__((ext_vector_type(8)));
typedef float v4f __attribute__((ext_vector_type(4)));

__device__ __forceinline__ short f2bf(float f) {
    union { float f; unsigned u; } x; x.f = f;
    unsigned r = (x.u + 0x7FFFu + ((x.u >> 16) & 1u)) >> 16;  // RNE
    return (short)r;
}
__device__ __forceinline__ float bf2f(short s) {
    union { unsigned u; float f; } x; x.u = ((unsigned)(unsigned short)s) << 16;
    return x.f;
}

__device__ __forceinline__ float wave_iscan(float v, int lane) {
#pragma unroll
    for (int d = 1; d < 64; d <<= 1) {
        float o = __shfl_up(v, (unsigned)d, 64);
        if (lane >= d) v += o;
    }
    return v;
}

// ---------------------------------------------------------------------------
// Fully fused SSD kernel. Grid (2 p-halves, NHEADS, BATCH) = 256 blocks.
// 8 waves: waves 0-3 compute (verified k_out/k_states frag math, half-p),
// waves 4-7 stage chunk k+1 into double-buffered LDS (reg-staged -> any
// layout incl. padded/frag).  Running scan state S lives in waves 0-1 regs;
// S_prev is published as bf16 frags in double-buffered sF.  One barrier/chunk.
// states/csum intermediates never touch global memory.
// ---------------------------------------------------------------------------
__global__ __launch_bounds__(512) void k_fused(
    const float* __restrict__ X, const float* __restrict__ A,
    const float* __restrict__ Bm, const float* __restrict__ Cm,
    float* __restrict__ Y)
{
    const int ph = blockIdx.x, hh = blockIdx.y, bb = blockIdx.z;
    const int tid = threadIdx.x;
    const int lane = tid & 63;
    const int wv = tid >> 6;           // 0..7
    const int W = wv & 3;              // consumer wave id (t-strip)
    const int qq = lane >> 4, nn = lane & 15;

    __shared__ __align__(16) float sXraw[2][CHUNK][PHALF + 1];  // 16.9 KB
    __shared__ __align__(16) short cFq[2][2048];  // C qk-frags (4 t-tiles, K=n zero-pad 16->32)
    __shared__ __align__(16) short bFq[2][2048];  // B qk-frags (B^T, K=n zero-pad)
    __shared__ __align__(16) short bFs[2][1024];  // B state-frags (K=t, 2 tiles)
    __shared__ __align__(16) short sF [2][1024];  // S^T frags (2 p-tiles, K=n zero-pad)
    __shared__ __align__(16) short gF [4096];     // G frags, per-wave regions
    __shared__ float araw[2][CHUNK];
    // total ~49 KB

    {   // zero-init: qk-frag K-pad rows (whole bufs) + sF (S_prev=0 for chunk 0)
        const v8s z8 = {0,0,0,0,0,0,0,0};
        if (tid < 512) { ((v8s*)cFq)[tid] = z8; ((v8s*)bFq)[tid] = z8; }
        if (tid < 256) ((v8s*)sF)[tid] = z8;
    }
    __syncthreads();

    auto stage = [&](int c, int buf) {
        const int ptid = tid & 255;
        const int t0c = bb * SEQLEN + c * CHUNK;
        // X half-strip: 64 rows x 32 floats (coalesced float4, 128B/row)
#pragma unroll
        for (int i = 0; i < 2; ++i) {
            const int idx = ptid + i * 256;
            const int row = idx >> 3, p4 = (idx & 7) * 4;
            const float4 v = *(const float4*)&X[((size_t)(t0c + row) * NHEADS + hh) * PDIM + ph * PHALF + p4];
            sXraw[buf][row][p4 + 0] = v.x; sXraw[buf][row][p4 + 1] = v.y;
            sXraw[buf][row][p4 + 2] = v.z; sXraw[buf][row][p4 + 3] = v.w;
        }
        // B (both frag layouts) + C
        {
            const int r = ptid >> 2, n0 = (ptid & 3) * 4;
            const float4 bv = *(const float4*)&Bm[((size_t)(t0c + r) * NHEADS + hh) * NDIM + n0];
            const int offq = ((r >> 4) * 64 + (n0 >> 3) * 16 + (r & 15)) * 8 + (n0 & 7);
            bFq[buf][offq + 0] = f2bf(bv.x); bFq[buf][offq + 1] = f2bf(bv.y);
            bFq[buf][offq + 2] = f2bf(bv.z); bFq[buf][offq + 3] = f2bf(bv.w);
            const int kk = r >> 5, q = (r >> 3) & 3, jj = r & 7;
            const int bs = (kk * 64 + q * 16) * 8 + jj;
            bFs[buf][bs + (n0 + 0) * 8] = f2bf(bv.x);
            bFs[buf][bs + (n0 + 1) * 8] = f2bf(bv.y);
            bFs[buf][bs + (n0 + 2) * 8] = f2bf(bv.z);
            bFs[buf][bs + (n0 + 3) * 8] = f2bf(bv.w);
            const float4 cv = *(const float4*)&Cm[((size_t)(t0c + r) * NHEADS + hh) * NDIM + n0];
            cFq[buf][offq + 0] = f2bf(cv.x); cFq[buf][offq + 1] = f2bf(cv.y);
            cFq[buf][offq + 2] = f2bf(cv.z); cFq[buf][offq + 3] = f2bf(cv.w);
        }
        if (ptid < CHUNK) araw[buf][ptid] = A[(size_t)(t0c + ptid) * NHEADS + hh];
    };

    if (wv >= 4) stage(0, 0);
    __syncthreads();

    v4f S = {0.f, 0.f, 0.f, 0.f};        // running scanned state, waves 0-1
    const v4f zero = {0.f, 0.f, 0.f, 0.f};

#pragma unroll 1
    for (int k = 0; k < NCHUNK; ++k) {
        const int cur = k & 1;
        if (wv >= 4) {
            if (k + 1 < NCHUNK) stage(k + 1, cur ^ 1);
        } else {
            const int t0c = bb * SEQLEN + k * CHUNK;
            // per-wave redundant A-scan (regs + shfl, no barrier needed)
            const float cum = wave_iscan(araw[cur][lane], lane);
            const float tot = __shfl(cum, 63, 64);
            float tcum[4];
#pragma unroll
            for (int r = 0; r < 4; ++r) tcum[r] = __shfl(cum, W * 16 + qq * 4 + r, 64);

            // qk^T MFMA + G build (verbatim k_out math; sCum reads -> shfl)
            const v8s cfrag = *(const v8s*)&cFq[cur][(W * 64 + lane) * 8];
#pragma unroll
            for (int st = 0; st < 4; ++st) {
                const int kk = st >> 1, q2 = (st & 1) * 2 + (nn >> 3), j2 = nn & 7;
                if (st <= W) {
                    const v8s bfrag = *(const v8s*)&bFq[cur][(st * 64 + lane) * 8];
                    v4f acc = __builtin_amdgcn_mfma_f32_16x16x32_bf16(cfrag, bfrag, zero, 0, 0, 0);
                    const float cums = __shfl(cum, st * 16 + nn, 64);
#pragma unroll
                    for (int r = 0; r < 4; ++r) {
                        const int t = W * 16 + qq * 4 + r;
                        const int s = st * 16 + nn;
                        const float g = (t >= s) ? acc[r] * __expf(tcum[r] - cums) : 0.f;
                        gF[((W * 2 + kk) * 64 + q2 * 16 + qq * 4 + r) * 8 + j2] = f2bf(g);
                    }
                } else if (kk == 0 || W >= 2) {
#pragma unroll
                    for (int r = 0; r < 4; ++r)
                        gF[((W * 2 + kk) * 64 + q2 * 16 + qq * 4 + r) * 8 + j2] = 0;
                }
            }
            const float et = __expf(__shfl(cum, W * 16 + nn, 64));
            v8s cefrag;
#pragma unroll
            for (int j = 0; j < 8; ++j) cefrag[j] = f2bf(bf2f(cfrag[j]) * et);

            const v8s ga0 = *(const v8s*)&gF[((W * 2 + 0) * 64 + lane) * 8];
            const bool usekk1 = (W >= 2);
            v8s ga1 = {0, 0, 0, 0, 0, 0, 0, 0};
            if (usekk1) ga1 = *(const v8s*)&gF[((W * 2 + 1) * 64 + lane) * 8];

            // Y = Y_off (C*et x S_prev^T) + Y_diag (G x X), x-frags read
            // directly from padded sXraw columns (no xF repack buffer)
            v4f ya[2];
#pragma unroll
            for (int nt = 0; nt < 2; ++nt) {
                const v8s sfrag = *(const v8s*)&sF[cur][(nt * 64 + lane) * 8];
                v4f a = __builtin_amdgcn_mfma_f32_16x16x32_bf16(cefrag, sfrag, zero, 0, 0, 0);
                v8s x0;
#pragma unroll
                for (int j = 0; j < 8; ++j) x0[j] = f2bf(sXraw[cur][qq * 8 + j][nt * 16 + nn]);
                a = __builtin_amdgcn_mfma_f32_16x16x32_bf16(ga0, x0, a, 0, 0, 0);
                if (usekk1) {
                    v8s x1;
#pragma unroll
                    for (int j = 0; j < 8; ++j) x1[j] = f2bf(sXraw[cur][32 + qq * 8 + j][nt * 16 + nn]);
                    a = __builtin_amdgcn_mfma_f32_16x16x32_bf16(ga1, x1, a, 0, 0, 0);
                }
                ya[nt] = a;
            }
#pragma unroll
            for (int r = 0; r < 4; ++r) {
                const int t = W * 16 + qq * 4 + r;
                float* yp = Y + ((size_t)(t0c + t) * NHEADS + hh) * PDIM + ph * PHALF + nn;
                yp[0]  = ya[0][r];
                yp[16] = ya[1][r];
            }

            // chunk state (waves 0-1, verbatim k_states math) + scan update
            if (W < 2) {
                v8s a0, a1;
#pragma unroll
                for (int j = 0; j < 8; ++j) {
                    const int tr = qq * 8 + j;
                    a0[j] = f2bf(sXraw[cur][tr][W * 16 + nn] *
                                 __expf(tot - __shfl(cum, tr, 64)));
                    a1[j] = f2bf(sXraw[cur][32 + tr][W * 16 + nn] *
                                 __expf(tot - __shfl(cum, 32 + tr, 64)));
                }
                const v8s b0 = *(const v8s*)&bFs[cur][(0 * 64 + lane) * 8];
                const v8s b1 = *(const v8s*)&bFs[cur][(1 * 64 + lane) * 8];
                v4f sa = __builtin_amdgcn_mfma_f32_16x16x32_bf16(a0, b0, zero, 0, 0, 0);
                sa = __builtin_amdgcn_mfma_f32_16x16x32_bf16(a1, b1, sa, 0, 0, 0);
                const float Et = __expf(tot);
#pragma unroll
                for (int r = 0; r < 4; ++r) S[r] = Et * S[r] + sa[r];
                // publish S_prev for next chunk into sF[nxt] (bf16 frag layout)
                short* d = &sF[cur ^ 1][0];
#pragma unroll
                for (int r = 0; r < 4; ++r)
                    d[(W * 64 + (nn >> 3) * 16 + qq * 4 + r) * 8 + (nn & 7)] = f2bf(S[r]);
            }
        }
        __syncthreads();
    }
}

// ---------------------------------------------------------------------------
extern "C" void kernel_launch(void* const* d_in, const int* in_sizes, int n_in,
                              void* d_out, int out_size, void* d_ws, size_t ws_size,
                              hipStream_t stream) {
    const float* X  = (const float*)d_in[0];
    const float* A  = (const float*)d_in[1];
    const float* Bm = (const float*)d_in[2];
    const float* Cm = (const float*)d_in[3];
    float* Y = (float*)d_out;
    (void)d_ws; (void)ws_size;

    dim3 grid(2, NHEADS, BATCH);
    k_fused<<<grid, 512, 0, stream>>>(X, A, Bm, Cm, Y);
}

// Round 3
// 336.118 us; speedup vs baseline: 1.1860x; 1.1860x over previous
//
#include <hip/hip_runtime.h>

#define BATCH   4
#define SEQLEN  4096
#define NHEADS  32
#define PDIM    64
#define NDIM    16
#define CHUNK   64
#define NCHUNK  64   // SEQLEN / CHUNK
#define PHALF   32

typedef short v8s __attribute__((ext_vector_type(8)));
typedef float v4f __attribute__((ext_vector_type(4)));

union V8U { v8s s; unsigned u[4]; };

__device__ __forceinline__ short f2bf(float f) {
    union { float f; unsigned u; } x; x.f = f;
    unsigned r = (x.u + 0x7FFFu + ((x.u >> 16) & 1u)) >> 16;  // RNE
    return (short)r;
}
__device__ __forceinline__ float bf2f(short s) {
    union { unsigned u; float f; } x; x.u = ((unsigned)(unsigned short)s) << 16;
    return x.f;
}
// HW packed f32->bf16 (RNE), 2 elems/inst — replaces software f2bf in hot paths.
__device__ __forceinline__ unsigned cvt_pk_bf16(float lo, float hi) {
    unsigned r;
    asm("v_cvt_pk_bf16_f32 %0, %1, %2" : "=v"(r) : "v"(lo), "v"(hi));
    return r;
}

__device__ __forceinline__ float wave_iscan(float v, int lane) {
#pragma unroll
    for (int d = 1; d < 64; d <<= 1) {
        float o = __shfl_up(v, (unsigned)d, 64);
        if (lane >= d) v += o;
    }
    return v;
}

// ---------------------------------------------------------------------------
// Fused SSD kernel v4: producer/consumer rebalanced.
// Grid (2 p-halves, NHEADS, BATCH) = 256 blocks, 512 threads (8 waves).
// Waves 4-7 (producers): stage chunk k+1 — A-scan (redundant per wave, 6
// shfl), X loaded TRANSPOSED from global and packed straight into bf16 MFMA
// A-frags (xF) and decay-weighted state frags (xSF) via v_cvt_pk_bf16_f32;
// B/C staged into frag layouts as before.  sCum published in LDS.
// Waves 0-3 (consumers): QK^T MFMA -> G through f32 LDS rows (conflict-free
// b32 writes, b128 row reads) -> Y MFMAs -> Y stores; waves 0-1 also run the
// state MFMAs + in-register scan S and publish sF for the next chunk.
// One barrier per chunk.
// ---------------------------------------------------------------------------
__global__ __launch_bounds__(512) void k_fused(
    const float* __restrict__ X, const float* __restrict__ A,
    const float* __restrict__ Bm, const float* __restrict__ Cm,
    float* __restrict__ Y)
{
    const int ph = blockIdx.x, hh = blockIdx.y, bb = blockIdx.z;
    const int tid = threadIdx.x;
    const int lane = tid & 63;
    const int wv = tid >> 6;           // 0..7
    const int W = wv & 3;              // consumer wave id (t-strip)
    const int qq = lane >> 4, nn = lane & 15;

    __shared__ __align__(16) short xF [2][4][64][8];  // X A-frags (kk*2+nt), 8 KB
    __shared__ __align__(16) short xSF[2][4][64][8];  // decay-X state A-frags, 8 KB
    __shared__ __align__(16) short cFq[2][2048];      // C qk-frags (K=n zero-pad), 8 KB
    __shared__ __align__(16) short bFq[2][2048];      // B qk-frags, 8 KB
    __shared__ __align__(16) short bFs[2][1024];      // B state-frags, 4 KB
    __shared__ __align__(16) short sF [2][1024];      // S^T frags, 4 KB
    __shared__ __align__(16) float gRaw[CHUNK][68];   // G f32 rows (pad 4), 17.4 KB
    __shared__ float sCum[2][CHUNK];                  // 0.5 KB
    // total ~58.9 KB

    {   // zero-init: qk-frag K-pad rows (whole bufs) + sF (S_prev=0 for chunk 0)
        const v8s z8 = {0,0,0,0,0,0,0,0};
        ((v8s*)cFq)[tid] = z8;                 // 512 v8s = both buffers
        ((v8s*)bFq)[tid] = z8;
        if (tid < 256) ((v8s*)sF)[tid] = z8;
    }

    auto stage = [&](int c, int buf) {
        const int t0c = bb * SEQLEN + c * CHUNK;
        // --- A-scan (each producer wave, redundant; 6 shfl) ---
        const float af = A[(size_t)(t0c + lane) * NHEADS + hh];
        float cum = wave_iscan(af, lane);
        const float tot = __shfl(cum, 63, 64);
        if (wv == 4) sCum[buf][lane] = cum;
        const float dec_own = __expf(tot - cum);
        // --- X transposed global load -> xF / xSF frags (one tile per wave) ---
        const int ti = wv - 4;                 // 0..3
        const int kk = ti >> 1, nt = ti & 1;
        const int p = ph * PHALF + nt * 16 + nn;
        const float* xb = X + ((size_t)(t0c + kk * 32 + qq * 8) * NHEADS + hh) * PDIM + p;
        float xv[8];
#pragma unroll
        for (int j = 0; j < 8; ++j) xv[j] = xb[(size_t)j * NHEADS * PDIM];
        float dv[8];
#pragma unroll
        for (int j = 0; j < 8; ++j) dv[j] = __shfl(dec_own, kk * 32 + qq * 8 + j, 64);
        V8U xf, xs;
#pragma unroll
        for (int j2 = 0; j2 < 4; ++j2) {
            xf.u[j2] = cvt_pk_bf16(xv[2*j2], xv[2*j2+1]);
            xs.u[j2] = cvt_pk_bf16(xv[2*j2] * dv[2*j2], xv[2*j2+1] * dv[2*j2+1]);
        }
        *(v8s*)&xF [buf][kk*2+nt][lane][0] = xf.s;
        *(v8s*)&xSF[buf][kk*2+nt][lane][0] = xs.s;
        // --- B (both frag layouts) + C over the 256 producer threads ---
        const int ptid = tid & 255;
        const int r = ptid >> 2, n0 = (ptid & 3) * 4;
        const float4 bv = *(const float4*)&Bm[((size_t)(t0c + r) * NHEADS + hh) * NDIM + n0];
        const int offq = ((r >> 4) * 64 + (n0 >> 3) * 16 + (r & 15)) * 8 + (n0 & 7);
        bFq[buf][offq + 0] = f2bf(bv.x); bFq[buf][offq + 1] = f2bf(bv.y);
        bFq[buf][offq + 2] = f2bf(bv.z); bFq[buf][offq + 3] = f2bf(bv.w);
        const int kb = r >> 5, qb = (r >> 3) & 3, jj = r & 7;
        const int bs = (kb * 64 + qb * 16) * 8 + jj;
        bFs[buf][bs + (n0 + 0) * 8] = f2bf(bv.x);
        bFs[buf][bs + (n0 + 1) * 8] = f2bf(bv.y);
        bFs[buf][bs + (n0 + 2) * 8] = f2bf(bv.z);
        bFs[buf][bs + (n0 + 3) * 8] = f2bf(bv.w);
        const float4 cv = *(const float4*)&Cm[((size_t)(t0c + r) * NHEADS + hh) * NDIM + n0];
        cFq[buf][offq + 0] = f2bf(cv.x); cFq[buf][offq + 1] = f2bf(cv.y);
        cFq[buf][offq + 2] = f2bf(cv.z); cFq[buf][offq + 3] = f2bf(cv.w);
    };

    __syncthreads();                  // init visible before staging overwrites
    if (wv >= 4) stage(0, 0);
    __syncthreads();

    v4f S = {0.f, 0.f, 0.f, 0.f};     // running scanned state, waves 0-1
    const v4f zero = {0.f, 0.f, 0.f, 0.f};

#pragma unroll 1
    for (int k = 0; k < NCHUNK; ++k) {
        const int cur = k & 1;
        if (wv >= 4) {
            if (k + 1 < NCHUNK) stage(k + 1, cur ^ 1);
        } else {
            const int t0c = bb * SEQLEN + k * CHUNK;
            const float* scm = &sCum[cur][0];
            float tcum[4];
#pragma unroll
            for (int r = 0; r < 4; ++r) tcum[r] = scm[W * 16 + qq * 4 + r];
            const v8s cfrag = *(const v8s*)&cFq[cur][(W * 64 + lane) * 8];

            // --- QK^T MFMA -> G (f32 rows, conflict-free b32 writes) ---
#pragma unroll
            for (int st = 0; st < 4; ++st) {
                if (st <= W) {
                    const v8s bfrag = *(const v8s*)&bFq[cur][(st * 64 + lane) * 8];
                    v4f acc = __builtin_amdgcn_mfma_f32_16x16x32_bf16(cfrag, bfrag, zero, 0, 0, 0);
                    const float cums = scm[st * 16 + nn];
#pragma unroll
                    for (int r = 0; r < 4; ++r) {
                        const int t = W * 16 + qq * 4 + r;
                        const int s = st * 16 + nn;
                        gRaw[t][s] = (t >= s) ? acc[r] * __expf(tcum[r] - cums) : 0.f;
                    }
                }
            }
            // zero-fill the G columns that are read but never computed
            if (W == 0) {
#pragma unroll
                for (int r = 0; r < 4; ++r) gRaw[qq * 4 + r][16 + nn] = 0.f;
            } else if (W == 2) {
#pragma unroll
                for (int r = 0; r < 4; ++r) gRaw[32 + qq * 4 + r][48 + nn] = 0.f;
            }

            // --- cefrag = C * exp(cum_t) (HW pack) ---
            const float et = __expf(scm[W * 16 + nn]);
            V8U cef;
#pragma unroll
            for (int j2 = 0; j2 < 4; ++j2)
                cef.u[j2] = cvt_pk_bf16(bf2f(cfrag[2*j2]) * et, bf2f(cfrag[2*j2+1]) * et);

            // --- G A-frags: row-contiguous b128 reads + HW pack ---
            V8U ga0u, ga1u;
            {
                const float* gr = &gRaw[W * 16 + nn][qq * 8];         // kk=0
#pragma unroll
                for (int j2 = 0; j2 < 4; ++j2) ga0u.u[j2] = cvt_pk_bf16(gr[2*j2], gr[2*j2+1]);
            }
            const bool usekk1 = (W >= 2);
            if (usekk1) {
                const float* gr = &gRaw[W * 16 + nn][32 + qq * 8];    // kk=1
#pragma unroll
                for (int j2 = 0; j2 < 4; ++j2) ga1u.u[j2] = cvt_pk_bf16(gr[2*j2], gr[2*j2+1]);
            }

            // --- Y = Y_off (Ce x S_prev^T) + Y_diag (G x X) ---
            v4f ya[2];
#pragma unroll
            for (int nt2 = 0; nt2 < 2; ++nt2) {
                const v8s sfrag = *(const v8s*)&sF[cur][(nt2 * 64 + lane) * 8];
                v4f a = __builtin_amdgcn_mfma_f32_16x16x32_bf16(cef.s, sfrag, zero, 0, 0, 0);
                const v8s x0 = *(const v8s*)&xF[cur][0 + nt2][lane][0];
                a = __builtin_amdgcn_mfma_f32_16x16x32_bf16(ga0u.s, x0, a, 0, 0, 0);
                if (usekk1) {
                    const v8s x1 = *(const v8s*)&xF[cur][2 + nt2][lane][0];
                    a = __builtin_amdgcn_mfma_f32_16x16x32_bf16(ga1u.s, x1, a, 0, 0, 0);
                }
                ya[nt2] = a;
            }
#pragma unroll
            for (int r = 0; r < 4; ++r) {
                const int t = W * 16 + qq * 4 + r;
                float* yp = Y + ((size_t)(t0c + t) * NHEADS + hh) * PDIM + ph * PHALF + nn;
                yp[0]  = ya[0][r];
                yp[16] = ya[1][r];
            }

            // --- chunk state (waves 0-1): frags pre-built by producers ---
            if (W < 2) {
                const v8s a0 = *(const v8s*)&xSF[cur][0 + W][lane][0];
                const v8s a1 = *(const v8s*)&xSF[cur][2 + W][lane][0];
                const v8s b0 = *(const v8s*)&bFs[cur][(0 * 64 + lane) * 8];
                const v8s b1 = *(const v8s*)&bFs[cur][(1 * 64 + lane) * 8];
                v4f sa = __builtin_amdgcn_mfma_f32_16x16x32_bf16(a0, b0, zero, 0, 0, 0);
                sa = __builtin_amdgcn_mfma_f32_16x16x32_bf16(a1, b1, sa, 0, 0, 0);
                const float Et = __expf(scm[63]);
#pragma unroll
                for (int r = 0; r < 4; ++r) S[r] = Et * S[r] + sa[r];
                short* d = &sF[cur ^ 1][0];
#pragma unroll
                for (int r = 0; r < 4; ++r)
                    d[(W * 64 + (nn >> 3) * 16 + qq * 4 + r) * 8 + (nn & 7)] = f2bf(S[r]);
            }
        }
        __syncthreads();
    }
}

// ---------------------------------------------------------------------------
extern "C" void kernel_launch(void* const* d_in, const int* in_sizes, int n_in,
                              void* d_out, int out_size, void* d_ws, size_t ws_size,
                              hipStream_t stream) {
    const float* X  = (const float*)d_in[0];
    const float* A  = (const float*)d_in[1];
    const float* Bm = (const float*)d_in[2];
    const float* Cm = (const float*)d_in[3];
    float* Y = (float*)d_out;
    (void)d_ws; (void)ws_size;

    dim3 grid(2, NHEADS, BATCH);
    k_fused<<<grid, 512, 0, stream>>>(X, A, Bm, Cm, Y);
}